// Round 2
// baseline (701.123 us; speedup 1.0000x reference)
//
#include <hip/hip_runtime.h>
#include <hip/hip_bf16.h>

#define B_ 8
#define N_ 4096
#define D_ 512
#define BM 64
#define BK 64
#define NTH 512

typedef __attribute__((ext_vector_type(8))) short bf16x8;
typedef __attribute__((ext_vector_type(4))) float f32x4;

__device__ __forceinline__ short f2bs(float x) {
  union { __hip_bfloat16 h; short s; } u;
  u.h = __float2bfloat16(x);
  return u.s;
}

__device__ __forceinline__ bf16x8 pack8(float4 a, float4 b) {
  bf16x8 r;
  r[0] = f2bs(a.x); r[1] = f2bs(a.y); r[2] = f2bs(a.z); r[3] = f2bs(a.w);
  r[4] = f2bs(b.x); r[5] = f2bs(b.y); r[6] = f2bs(b.z); r[7] = f2bs(b.w);
  return r;
}

// ---------------- kernel 1: rnorm[b*N+n] = 1/||tgt[b,n,:]|| ----------------
__global__ void __launch_bounds__(256) rnorm_kernel(const float* __restrict__ tgt,
                                                    float* __restrict__ rn) {
  int row  = blockIdx.x * 4 + (threadIdx.x >> 6);
  int lane = threadIdx.x & 63;
  const float* p = tgt + (size_t)row * D_ + lane * 8;
  float4 a = *(const float4*)p;
  float4 b = *(const float4*)(p + 4);
  float s = a.x*a.x + a.y*a.y + a.z*a.z + a.w*a.w
          + b.x*b.x + b.y*b.y + b.z*b.z + b.w*b.w;
  #pragma unroll
  for (int m = 32; m >= 1; m >>= 1) s += __shfl_xor(s, m, 64);
  if (lane == 0) rn[row] = rsqrtf(s);
}

// ---------------- kernel 2: fused  out = tanh(Xn Xn^T) * tgt ----------------
// Per block: 64 q-rows of one batch.  Loop over 64-row K/V tiles:
//   stage raw tgt tile (bf16, swizzled) -> S = Q*K^T (MFMA, Q in regs)
//   -> scale by rnorm_q*rnorm_k, tanh, P->LDS ; transpose KV->KVt
//   -> out += P * KVt (MFMA, [64x64] wave tiles)
__global__ void __launch_bounds__(NTH, 2) fused_kernel(const float* __restrict__ tgt,
                                                       const float* __restrict__ rn,
                                                       float* __restrict__ out) {
  __shared__ ushort KV [BK * D_];   // [m][d] row 1024B, swizzled   64 KB
  __shared__ ushort KVt[D_ * BK];   // [d][m] row  128B, swizzled   64 KB
  __shared__ ushort Pl [BM * BK];   // [n][m] row  128B, swizzled    8 KB

  // XCD-aware swizzle: batch k -> XCD k (per-batch 8MB working set stays in one L2)
  int id  = blockIdx.x;
  int swz = (id & 7) * 64 + (id >> 3);
  const int b  = swz >> 6;
  const int q0 = (swz & 63) * BM;

  const int tid  = threadIdx.x;
  const int lane = tid & 63;
  const int w    = tid >> 6;

  const size_t base = (size_t)b * ((size_t)N_ * D_);
  const float* T   = tgt + base;
  const float* rnb = rn + b * N_;

  // ---- S-phase geometry: wave w -> S rows [rq0,rq0+16), cols [kc0,kc0+32)
  const int rq0 = (w >> 1) * 16;
  const int kc0 = (w & 1) * 32;

  // Q fragments in registers: rows q0+rq0+(lane&15), k-chunks of 8
  bf16x8 qf[16];
  {
    const float* qp = T + (size_t)(q0 + rq0 + (lane & 15)) * D_ + (lane >> 4) * 8;
    #pragma unroll
    for (int kk = 0; kk < 16; ++kk) {
      float4 f0 = *(const float4*)(qp + kk * 32);
      float4 f1 = *(const float4*)(qp + kk * 32 + 4);
      qf[kk] = pack8(f0, f1);
    }
  }
  float rqv[4];
  #pragma unroll
  for (int j = 0; j < 4; ++j) rqv[j] = rnb[q0 + rq0 + (lane >> 4) * 4 + j];

  // PV accumulators: wave w owns d-cols [dc, dc+64): 4x4 frags of 16x16
  f32x4 acc[4][4] = {};
  const int dc = w * 64;

  for (int mt = 0; mt < N_ / BK; ++mt) {
    const int m0 = mt * BK;

    // ---- stage KV tile [64 x 512] raw tgt -> bf16, swizzled
    {
      const int r = tid >> 3;                       // m-row 0..63
      const float* gp = T + (size_t)(m0 + r) * D_;
      #pragma unroll
      for (int c = 0; c < 8; ++c) {
        int de = (tid & 7) * 8 + c * 64;            // d element
        float4 f0 = *(const float4*)(gp + de);
        float4 f1 = *(const float4*)(gp + de + 4);
        bf16x8 v = pack8(f0, f1);
        *(bf16x8*)&KV[(r * 1024 + ((de * 2) ^ ((r & 7) << 4))) >> 1] = v;
      }
    }
    __syncthreads();

    // ---- S = Q * K^T (raw dots, fp32 acc)
    f32x4 sacc[2] = {};
    #pragma unroll
    for (int kk = 0; kk < 16; ++kk) {
      int cb = kk * 64 + (lane >> 4) * 16;          // k byte offset in row
      #pragma unroll
      for (int f = 0; f < 2; ++f) {
        int m = kc0 + f * 16 + (lane & 15);
        bf16x8 bfr = *(const bf16x8*)&KV[(m * 1024 + (cb ^ ((m & 7) << 4))) >> 1];
        sacc[f] = __builtin_amdgcn_mfma_f32_16x16x32_bf16(qf[kk], bfr, sacc[f], 0, 0, 0);
      }
    }

    // ---- epilogue: scale by rnorms, tanh, write P (bf16, swizzled)
    #pragma unroll
    for (int f = 0; f < 2; ++f) {
      int col = kc0 + f * 16 + (lane & 15);
      float rk = rnb[m0 + col];
      #pragma unroll
      for (int j = 0; j < 4; ++j) {
        int row = rq0 + (lane >> 4) * 4 + j;
        float s = sacc[f][j] * rqv[j] * rk;
        float e = __expf(2.0f * s);
        float t = (e - 1.0f) * __builtin_amdgcn_rcpf(e + 1.0f);
        Pl[(row * 128 + ((col * 2) ^ ((row & 7) << 4))) >> 1] = (ushort)f2bs(t);
      }
    }

    // ---- transpose KV -> KVt (lane = m-row; b16 writes hit all 32 banks)
    {
      const int m = tid & 63;
      #pragma unroll
      for (int i = 0; i < 8; ++i) {
        int de = ((tid >> 6) * 8 + i) * 8;          // d chunk base
        bf16x8 v = *(const bf16x8*)&KV[(m * 1024 + ((de * 2) ^ ((m & 7) << 4))) >> 1];
        #pragma unroll
        for (int e = 0; e < 8; ++e) {
          int d = de + e;
          KVt[(d * 128 + ((m * 2) ^ ((d & 7) << 4))) >> 1] = (ushort)v[e];
        }
      }
    }
    __syncthreads();

    // ---- out += P * V   (wave tile [64 n x 64 d], 4x4 frags, 2 k-steps)
    #pragma unroll
    for (int ks = 0; ks < 2; ++ks) {
      int kb = ks * 64 + (lane >> 4) * 16;          // m byte offset in row
      bf16x8 pa[4], vb[4];
      #pragma unroll
      for (int ai = 0; ai < 4; ++ai) {
        int row = ai * 16 + (lane & 15);
        pa[ai] = *(const bf16x8*)&Pl[(row * 128 + (kb ^ ((row & 7) << 4))) >> 1];
      }
      #pragma unroll
      for (int bj = 0; bj < 4; ++bj) {
        int d = dc + bj * 16 + (lane & 15);
        vb[bj] = *(const bf16x8*)&KVt[(d * 128 + (kb ^ ((d & 7) << 4))) >> 1];
      }
      #pragma unroll
      for (int ai = 0; ai < 4; ++ai)
        #pragma unroll
        for (int bj = 0; bj < 4; ++bj)
          acc[ai][bj] = __builtin_amdgcn_mfma_f32_16x16x32_bf16(pa[ai], vb[bj], acc[ai][bj], 0, 0, 0);
    }
    __syncthreads();   // before next stage overwrites KV... (also protects Pl/KVt)
  }

  // ---- write out [64 x 512] fp32
  {
    float* op = out + base;
    #pragma unroll
    for (int ai = 0; ai < 4; ++ai) {
      #pragma unroll
      for (int j = 0; j < 4; ++j) {
        int row = q0 + ai * 16 + (lane >> 4) * 4 + j;
        #pragma unroll
        for (int bj = 0; bj < 4; ++bj) {
          int col = dc + bj * 16 + (lane & 15);
          op[(size_t)row * D_ + col] = acc[ai][bj][j];
        }
      }
    }
  }
}

extern "C" void kernel_launch(void* const* d_in, const int* in_sizes, int n_in,
                              void* d_out, int out_size, void* d_ws, size_t ws_size,
                              hipStream_t stream) {
  const float* tgt = (const float*)d_in[0];
  float* outp = (float*)d_out;
  float* rn   = (float*)d_ws;                // B_*N_ floats = 128 KB

  rnorm_kernel<<<dim3((B_ * N_) / 4), dim3(256), 0, stream>>>(tgt, rn);
  fused_kernel<<<dim3(B_ * (N_ / BM)), dim3(NTH), 0, stream>>>(tgt, rn, outp);
}